// Round 1
// baseline (217.130 us; speedup 1.0000x reference)
//
#include <hip/hip_runtime.h>

// Smoother: out = max(pred, (reflect-pad moving-sum(K=501) + bias)/K)
// pred: [B=8, T=16384, C=128] fp32, C contiguous.
// One lane per channel (scalar fp32), 128-lane groups slide along t.
// TT=128 outputs per group -> 1024 groups -> 8 waves/CU.

constexpr int B  = 8;
constexpr int T  = 16384;
constexpr int C  = 128;
constexpr int K  = 501;
constexpr int Pp = 250;
constexpr int TT = 128;               // outputs per group
constexpr int GROUPS_PER_BLOCK = 2;   // 2 x 128 lanes = 256 threads/block
constexpr int BLOCK = C * GROUPS_PER_BLOCK;

__device__ __forceinline__ int ridx(int j) {
    // jnp.pad mode="reflect": no edge repeat.  j in [-(Pp+1), T+Pp] here.
    j = (j < 0) ? -j : j;
    j = (j >= T) ? (2 * T - 2 - j) : j;
    return j;
}

__global__ __launch_bounds__(BLOCK) void smoother_kernel(
    const float* __restrict__ pred, const float* __restrict__ bias,
    float* __restrict__ out) {
    const int group = blockIdx.x * GROUPS_PER_BLOCK + (threadIdx.x >> 7);
    const int c     = threadIdx.x & (C - 1);
    const int tiles_per_b = T / TT;
    const int b  = group / tiles_per_b;
    const int t0 = (group % tiles_per_b) * TT;

    const float* base  = pred + (size_t)b * T * C + c;
    float*       obase = out  + (size_t)b * T * C + c;

    const float rk  = 1.0f / (float)K;
    const float brk = bias[0] * rk;   // fold bias into the fma

    // ---- init: window sum for t = t0, covering [t0-250, t0+250] ----
    float s = 0.0f;
    if (t0 - Pp >= 0 && t0 + Pp < T) {
        // interior: no reflection needed
        #pragma unroll 8
        for (int j = t0 - Pp; j <= t0 + Pp; ++j)
            s += base[(size_t)j * C];
    } else {
        #pragma unroll 4
        for (int j = t0 - Pp; j <= t0 + Pp; ++j)
            s += base[(size_t)ridx(j) * C];
    }

    // ---- slide: out[t] = max(pred[t], s/K + bias/K); s += x[t+251]-x[t-250]
    if (t0 - Pp >= 0 && t0 + TT + Pp < T) {
        // interior tile: reflect-free fast loop
        #pragma unroll 4
        for (int t = t0; t < t0 + TT; ++t) {
            const float center = base[(size_t)t * C];
            const float sm     = fmaf(s, rk, brk);
            obase[(size_t)t * C] = fmaxf(center, sm);
            s += base[(size_t)(t + Pp + 1) * C] - base[(size_t)(t - Pp) * C];
        }
    } else {
        #pragma unroll 2
        for (int t = t0; t < t0 + TT; ++t) {
            const float center = base[(size_t)t * C];
            const float sm     = fmaf(s, rk, brk);
            obase[(size_t)t * C] = fmaxf(center, sm);
            s += base[(size_t)ridx(t + Pp + 1) * C]
               - base[(size_t)ridx(t - Pp) * C];
        }
    }
}

extern "C" void kernel_launch(void* const* d_in, const int* in_sizes, int n_in,
                              void* d_out, int out_size, void* d_ws, size_t ws_size,
                              hipStream_t stream) {
    const float* pred = (const float*)d_in[0];
    const float* bias = (const float*)d_in[1];
    float*       out  = (float*)d_out;

    const int groups = B * (T / TT);                 // 1024
    const int blocks = groups / GROUPS_PER_BLOCK;    // 512
    smoother_kernel<<<blocks, BLOCK, 0, stream>>>(pred, bias, out);
}

// Round 3
// 169.745 us; speedup vs baseline: 1.2792x; 1.2792x over previous
//
#include <hip/hip_runtime.h>

// Smoother: out = max(pred, (reflect-pad moving-sum(K=501) + bias)/K)
// pred: [B=8, T=16384, C=128] fp32.
// Round 3 (= round 2 w/ compile fix): clang ext_vector float2 lanes,
// 4 consecutive t-tiles per block, XCD swizzle (one batch per XCD),
// nontemporal stores, deep-ILP init (4 rotating accumulators).

typedef float f2 __attribute__((ext_vector_type(2)));

constexpr int B  = 8;
constexpr int T  = 16384;
constexpr int C  = 128;
constexpr int K  = 501;
constexpr int Pp = 250;
constexpr int TT = 128;    // outputs per wave
constexpr int WPB = 4;     // waves per block -> block covers 512 consecutive t
constexpr int BLOCK = 64 * WPB;
constexpr int RS = C / 2;  // row stride in f2 units (64)

__device__ __forceinline__ int ridx(int j) {
    j = (j < 0) ? -j : j;
    return (j >= T) ? (2 * T - 2 - j) : j;
}

__global__ __launch_bounds__(BLOCK) void smoother_kernel(
    const float* __restrict__ pred, const float* __restrict__ bias,
    float* __restrict__ out) {
    // 256 blocks. Swizzle: XCD = blockIdx%8 owns all 32 blocks of batch b=XCD.
    const int linear = (blockIdx.x & 7) * 32 + (blockIdx.x >> 3);
    const int b    = linear >> 5;   // /32
    const int quad = linear & 31;   // 32 quads x 512 t each
    const int wave = threadIdx.x >> 6;
    const int lane = threadIdx.x & 63;
    const int t0 = quad * (TT * WPB) + wave * TT;

    const f2* base  = (const f2*)(pred + (size_t)b * T * C) + lane;
    f2*       obase = (f2*)(out + (size_t)b * T * C) + lane;

    const float rk  = 1.0f / (float)K;
    const float brk = bias[0] * rk;

    const bool interior = (t0 - Pp >= 0) && (t0 + TT + Pp < T);

    f2 s;
    if (interior) {
        // ---- init: sum rows [t0-250, t0+250], 4 rotating accumulators ----
        const f2* p = base + (t0 - Pp) * RS;
        f2 s0 = {0.f, 0.f}, s1 = {0.f, 0.f}, s2 = {0.f, 0.f}, s3 = {0.f, 0.f};
        int j = 0;
        #pragma unroll 4
        for (; j + 4 <= K; j += 4) {
            f2 a0 = p[(j + 0) * RS];
            f2 a1 = p[(j + 1) * RS];
            f2 a2 = p[(j + 2) * RS];
            f2 a3 = p[(j + 3) * RS];
            s0 += a0; s1 += a1; s2 += a2; s3 += a3;
        }
        s0 += p[j * RS];            // K=501 remainder
        s = (s0 + s1) + (s2 + s3);

        // ---- slide ----
        #pragma unroll 4
        for (int t = t0; t < t0 + TT; ++t) {
            f2 cen = base[t * RS];
            f2 nw  = base[(t + Pp + 1) * RS];
            f2 od  = base[(t - Pp) * RS];
            f2 o;
            o.x = fmaxf(cen.x, fmaf(s.x, rk, brk));
            o.y = fmaxf(cen.y, fmaf(s.y, rk, brk));
            __builtin_nontemporal_store(o, &obase[t * RS]);
            s += nw - od;
        }
    } else {
        // ---- boundary path with reflection ----
        s.x = 0.f; s.y = 0.f;
        #pragma unroll 4
        for (int j = t0 - Pp; j <= t0 + Pp; ++j)
            s += base[ridx(j) * RS];
        #pragma unroll 2
        for (int t = t0; t < t0 + TT; ++t) {
            f2 cen = base[t * RS];
            f2 nw  = base[ridx(t + Pp + 1) * RS];
            f2 od  = base[ridx(t - Pp) * RS];
            f2 o;
            o.x = fmaxf(cen.x, fmaf(s.x, rk, brk));
            o.y = fmaxf(cen.y, fmaf(s.y, rk, brk));
            __builtin_nontemporal_store(o, &obase[t * RS]);
            s += nw - od;
        }
    }
}

extern "C" void kernel_launch(void* const* d_in, const int* in_sizes, int n_in,
                              void* d_out, int out_size, void* d_ws, size_t ws_size,
                              hipStream_t stream) {
    const float* pred = (const float*)d_in[0];
    const float* bias = (const float*)d_in[1];
    float*       out  = (float*)d_out;

    const int blocks = B * (T / (TT * WPB));   // 8 * 32 = 256
    smoother_kernel<<<blocks, BLOCK, 0, stream>>>(pred, bias, out);
}